// Round 11
// baseline (201.084 us; speedup 1.0000x reference)
//
#include <hip/hip_runtime.h>
#include <cstdint>
#include <cstddef>

// GPT-2 attention block, bf16 MFMA. B=2, S=2048, NX=1024, H=16, D=64.
// ws layout (48 MiB used):
//   [0,8M)    xb   : x as bf16            [4096][1024]
//   [8M,14M)  wTa  : w_attn^T as bf16     [3072][1024]
//   [14M,16M) wTp  : w_proj^T as bf16     [1024][1024]
//   [16M,40M) qkv  : bf16                 [4096][3072]
//   [40M,48M) abuf : attn out bf16        [4096][1024]

typedef __bf16 bf16;
typedef __bf16 bf16x8 __attribute__((ext_vector_type(8)));
typedef __bf16 bf16x4 __attribute__((ext_vector_type(4)));
typedef float f32x4 __attribute__((ext_vector_type(4)));
typedef float f32x16 __attribute__((ext_vector_type(16)));

#define MFMA16(a, b, c) __builtin_amdgcn_mfma_f32_16x16x32_bf16(a, b, c, 0, 0, 0)
#define MFMA32(a, b, c) __builtin_amdgcn_mfma_f32_32x32x16_bf16(a, b, c, 0, 0, 0)

typedef const __attribute__((address_space(1))) void* gas_ptr;
typedef __attribute__((address_space(3))) void* las_ptr;
__device__ __forceinline__ void async16(const void* g, void* l) {
    __builtin_amdgcn_global_load_lds((gas_ptr)g, (las_ptr)l, 16, 0, 0);
}
__device__ __forceinline__ float exp2f_fast(float x) { return __builtin_amdgcn_exp2f(x); }
__device__ __forceinline__ uint32_t pkbf(float a, float b) {
    union { bf16 x[2]; uint32_t u; } t;
    t.x[0] = (bf16)a; t.x[1] = (bf16)b;
    return t.u;
}

#define WAITVM4()   asm volatile("s_waitcnt vmcnt(4)" ::: "memory")
#define WAITVM0()   asm volatile("s_waitcnt vmcnt(0)" ::: "memory")
#define WAITLGKM0() asm volatile("s_waitcnt lgkmcnt(0)" ::: "memory")
#define SCHEDB()    __builtin_amdgcn_sched_barrier(0)

// ---------------- fused prep: cvt x->bf16 + transpose both weights (R7) ----------------
__global__ __launch_bounds__(256) void prep_kernel(const float* __restrict__ x, bf16* __restrict__ xb,
                                                   const float* __restrict__ wa, bf16* __restrict__ wTa,
                                                   const float* __restrict__ wp, bf16* __restrict__ wTp) {
    __shared__ float tile[32][33];
    const int bid = blockIdx.x, tid = threadIdx.x;
    if (bid < 4096) {
        int i = (bid * 256 + tid) * 4;
        float4 v = *reinterpret_cast<const float4*>(x + i);
        bf16x4 o;
        o[0] = (bf16)v.x; o[1] = (bf16)v.y; o[2] = (bf16)v.z; o[3] = (bf16)v.w;
        *reinterpret_cast<bf16x4*>(xb + i) = o;
        return;
    }
    const float* in; bf16* out; int N, t;
    if (bid < 7168) { t = bid - 4096; in = wa; out = wTa; N = 3072; }
    else            { t = bid - 7168; in = wp; out = wTp; N = 1024; }
    const int K = 1024;
    int bx = t % (N >> 5), by = t / (N >> 5);
    int n0 = bx * 32, k0 = by * 32, tx = tid & 31, ty = tid >> 5;
#pragma unroll
    for (int i = 0; i < 32; i += 8)
        tile[ty + i][tx] = in[(size_t)(k0 + ty + i) * N + n0 + tx];
    __syncthreads();
#pragma unroll
    for (int i = 0; i < 32; i += 8)
        out[(size_t)(n0 + ty + i) * K + k0 + tx] = (bf16)tile[tx][ty + i];
}

// ---------------- bf16 GEMM 256x256, BK=32, 4-slot LDS ring, counted-vmcnt (R10, best) ----------------
__global__ __launch_bounds__(512, 2) void gemm256_kernel(const bf16* __restrict__ A,
                                                         const bf16* __restrict__ Bt,
                                                         const float* __restrict__ bias,
                                                         bf16* __restrict__ Cout,
                                                         int M, int N, int K) {
    __shared__ bf16 lds[4][2][8192];   // [slot][A=0/B=1][256 rows x 32 k, packed] = 128 KiB
    const int tid = threadIdx.x;
    const int w = tid >> 6, l = tid & 63;
    const int lane16 = l & 15, quad = l >> 4;
    const int wm = w >> 2, wn = w & 3;

    const int nwg = gridDim.x * gridDim.y;   // 192, %8==0
    const int lin = blockIdx.x + gridDim.x * blockIdx.y;
    const int q8 = nwg >> 3;
    const int swz = (lin & 7) * q8 + (lin >> 3);
    const int bx = swz % gridDim.x, by = swz / gridDim.x;
    const int row0 = by * 256, col0 = bx * 256;

    const int sR = tid >> 3, sposr = tid & 7;
    const int spos2 = sposr ^ (sR & 7);
    const int sr2 = 2 * sR + (spos2 >> 2);
    const int sgk = (spos2 & 3) * 8;
    auto stageA = [&](int slot, int tile, int h) {
        async16(A + (size_t)(row0 + h * 128 + sr2) * K + (tile << 5) + sgk,
                &lds[slot][0][h * 4096 + tid * 8]);
    };
    auto stageB = [&](int slot, int tile, int h) {
        async16(Bt + (size_t)(col0 + h * 128 + sr2) * K + (tile << 5) + sgk,
                &lds[slot][1][h * 4096 + tid * 8]);
    };

    const int fpos = (((lane16 & 1) << 2) + quad) ^ (lane16 >> 1);
    const int fbA = wm * 4096 + (lane16 >> 1) * 64 + fpos * 8;
    const int fbB = wn * 2048 + (lane16 >> 1) * 64 + fpos * 8;

    f32x4 zero4 = {0.f, 0.f, 0.f, 0.f};
    f32x4 acc[8][4];
#pragma unroll
    for (int i = 0; i < 8; ++i)
#pragma unroll
        for (int j = 0; j < 4; ++j) acc[i][j] = zero4;

#pragma unroll
    for (int h = 0; h < 2; ++h) { stageA(0, 0, h); }
#pragma unroll
    for (int h = 0; h < 2; ++h) { stageB(0, 0, h); }
#pragma unroll
    for (int h = 0; h < 2; ++h) { stageA(1, 1, h); }
#pragma unroll
    for (int h = 0; h < 2; ++h) { stageB(1, 1, h); }
    WAITVM4();
    SCHEDB();
    __builtin_amdgcn_s_barrier();

    const int ntiles = K >> 5;   // 32
    for (int t = 0; t < ntiles; ++t) {
        const int slot = t & 3;
        const int ps = (t + 2) & 3;
        const bool pre = (t + 2) < ntiles;
        const bf16* Ap = &lds[slot][0][0];
        const bf16* Bp = &lds[slot][1][0];

        bf16x8 bfr[4], af[4];
#pragma unroll
        for (int jn = 0; jn < 4; ++jn)
            bfr[jn] = *reinterpret_cast<const bf16x8*>(&Bp[fbB + jn * 512]);
#pragma unroll
        for (int i = 0; i < 4; ++i)
            af[i] = *reinterpret_cast<const bf16x8*>(&Ap[fbA + i * 512]);
        if (pre) { stageA(ps, t + 2, 0); stageA(ps, t + 2, 1); }
        SCHEDB();
        __builtin_amdgcn_s_barrier();
        WAITLGKM0();
        SCHEDB();
        __builtin_amdgcn_s_setprio(1);
#pragma unroll
        for (int i = 0; i < 4; ++i)
#pragma unroll
            for (int jn = 0; jn < 4; ++jn) acc[i][jn] = MFMA16(af[i], bfr[jn], acc[i][jn]);
        __builtin_amdgcn_s_setprio(0);
        SCHEDB();
        __builtin_amdgcn_s_barrier();

#pragma unroll
        for (int i = 0; i < 4; ++i)
            af[i] = *reinterpret_cast<const bf16x8*>(&Ap[fbA + (4 + i) * 512]);
        if (pre) { stageB(ps, t + 2, 0); stageB(ps, t + 2, 1); }
        SCHEDB();
        __builtin_amdgcn_s_barrier();
        WAITLGKM0();
        SCHEDB();
        __builtin_amdgcn_s_setprio(1);
#pragma unroll
        for (int i = 0; i < 4; ++i)
#pragma unroll
            for (int jn = 0; jn < 4; ++jn) acc[4 + i][jn] = MFMA16(af[i], bfr[jn], acc[4 + i][jn]);
        __builtin_amdgcn_s_setprio(0);
        if (pre) { WAITVM4(); } else { WAITVM0(); }
        SCHEDB();
        __builtin_amdgcn_s_barrier();
    }

#pragma unroll
    for (int i = 0; i < 8; ++i)
#pragma unroll
        for (int jn = 0; jn < 4; ++jn)
#pragma unroll
            for (int r = 0; r < 4; ++r) {
                int row = row0 + wm * 128 + i * 16 + quad * 4 + r;
                int col = col0 + wn * 64 + jn * 16 + lane16;
                Cout[(size_t)row * N + col] = (bf16)(acc[i][jn][r] + bias[col]);
            }
}

// ---------------- bf16 GEMM 64x128, BK=64, XOR-swizzled LDS, dbuf (R4/R7) ----------------
template <int OUT_BF16>
__global__ __launch_bounds__(256) void gemm64k_kernel(const bf16* __restrict__ A,
                                                      const bf16* __restrict__ Bt,
                                                      const float* __restrict__ bias,
                                                      void* __restrict__ Cout,
                                                      int M, int N, int K) {
    __shared__ bf16 Alds[2][64 * 64];
    __shared__ bf16 Blds[2][128 * 64];
    const int tid = threadIdx.x;
    const int w = tid >> 6, l = tid & 63;
    const int lane16 = l & 15, quad = l >> 4;
    const int wr = w >> 1, wc = w & 1;
    const int row0 = blockIdx.y * 64, col0 = blockIdx.x * 128;

    f32x4 zero4 = {0.f, 0.f, 0.f, 0.f};
    f32x4 acc[2][4];
#pragma unroll
    for (int i = 0; i < 2; ++i)
#pragma unroll
        for (int j = 0; j < 4; ++j) acc[i][j] = zero4;

    auto stage = [&](int buf, int k0) {
#pragma unroll
        for (int c = 0; c < 2; ++c) {
            int idx = c * 256 + tid;
            int r = idx >> 3, cc = idx & 7, gc = cc ^ (r & 7);
            async16(A + (size_t)(row0 + r) * K + k0 + gc * 8, &Alds[buf][idx * 8]);
        }
#pragma unroll
        for (int c = 0; c < 4; ++c) {
            int idx = c * 256 + tid;
            int r = idx >> 3, cc = idx & 7, gc = cc ^ (r & 7);
            async16(Bt + (size_t)(col0 + r) * K + k0 + gc * 8, &Blds[buf][idx * 8]);
        }
    };

    stage(0, 0);
    const int niter = K >> 6;
    for (int it = 0; it < niter; ++it) {
        const int cur = it & 1;
        __syncthreads();
        if (it + 1 < niter) stage(cur ^ 1, (it + 1) << 6);
        bf16x8 af[2][2], bfr[4][2];
#pragma unroll
        for (int i = 0; i < 2; ++i) {
            int r = 32 * wr + 16 * i + lane16;
#pragma unroll
            for (int ks = 0; ks < 2; ++ks) {
                int cc = (quad + 4 * ks) ^ (r & 7);
                af[i][ks] = *reinterpret_cast<const bf16x8*>(&Alds[cur][r * 64 + cc * 8]);
            }
        }
#pragma unroll
        for (int j = 0; j < 4; ++j) {
            int r = 64 * wc + 16 * j + lane16;
#pragma unroll
            for (int ks = 0; ks < 2; ++ks) {
                int cc = (quad + 4 * ks) ^ (r & 7);
                bfr[j][ks] = *reinterpret_cast<const bf16x8*>(&Blds[cur][r * 64 + cc * 8]);
            }
        }
#pragma unroll
        for (int ks = 0; ks < 2; ++ks)
#pragma unroll
            for (int i = 0; i < 2; ++i)
#pragma unroll
                for (int j = 0; j < 4; ++j) acc[i][j] = MFMA16(af[i][ks], bfr[j][ks], acc[i][j]);
    }

#pragma unroll
    for (int i = 0; i < 2; ++i)
#pragma unroll
        for (int j = 0; j < 4; ++j)
#pragma unroll
            for (int r = 0; r < 4; ++r) {
                int row = row0 + 32 * wr + 16 * i + quad * 4 + r;
                int col = col0 + 64 * wc + 16 * j + lane16;
                float v = acc[i][j][r] + bias[col];
                if (OUT_BF16)
                    reinterpret_cast<bf16*>(Cout)[(size_t)row * N + col] = (bf16)v;
                else
                    reinterpret_cast<float*>(Cout)[(size_t)row * N + col] = v;
            }
}

// ---------------- flash attention: 32x32 MFMA + in-reg softmax (R7) + split-QK^T chains ----------------
// Only change vs R7: QK^T's 4 DEPENDENT MFMA32s (st accumulates over s=0..3,
// ~100-120cy serial latency/tile) are split into two independent half-chains
// st_a (d in [0,32)) and st_b (d in [32,64)), summed with 16 v_add_f32. The
// kernel is chain-latency-bound (two architectures measured within 1us), so
// halving the longest dependent run is the remaining lever (T15 mechanism).
__global__ __launch_bounds__(256, 4) void attn_kernel(const bf16* __restrict__ qkv,
                                                      bf16* __restrict__ aout) {
    const int S = 2048;
    const int bh = blockIdx.x;
    const int b = bh >> 4, hd = bh & 15;
    const int rr = blockIdx.y >> 3, j = blockIdx.y & 7;
    const int qt = (rr == 0) ? (31 - j) : (rr == 1) ? (16 + j) : (rr == 2) ? (15 - j) : j;
    const int nkt = qt + 1;
    const int tid = threadIdx.x, w = tid >> 6, l = tid & 63;
    const int lane32 = l & 31, h = l >> 5;
    const int qh = w & 1, kh = w >> 1;

    __shared__ bf16 Klds[2][64 * 64];   // [k][d] swizzled; re-used as f32 Obuf post-loop
    __shared__ bf16 Vt[2][64 * 64];     // [d][k] swizzled
    __shared__ float Lbuf[2][2][32];    // [kh][qh][q-row]

    const bf16* base = qkv + (size_t)b * S * 3072;
    const float qscale = 0.125f * 1.4426950408889634f;
    const float NEGs = -10000.0f * 1.4426950408889634f;

    bf16x8 qf[4];
    {
        const bf16* qp = base + (size_t)(qt * 64 + qh * 32 + lane32) * 3072 + hd * 64;
#pragma unroll
        for (int s = 0; s < 4; ++s) {
            bf16x8 t = *reinterpret_cast<const bf16x8*>(qp + s * 16 + h * 8);
#pragma unroll
            for (int jj = 0; jj < 8; ++jj) t[jj] = (bf16)((float)t[jj] * qscale);
            qf[s] = t;
        }
    }

    f32x16 oacc[2];
#pragma unroll
    for (int dt = 0; dt < 2; ++dt)
#pragma unroll
        for (int i = 0; i < 16; ++i) oacc[dt][i] = 0.f;
    float lsum = 0.f;

    const int kr = tid >> 3, kcc = tid & 7;
    const int vp = tid & 31, vd = (tid >> 5) * 8;
    bf16x8 kreg0, kreg1, vreg0, vreg1;
    auto load_tile = [&](int kt) {
        const bf16* tb = base + (size_t)(kt * 64) * 3072;
        kreg0 = *reinterpret_cast<const bf16x8*>(tb + (size_t)kr * 3072 + 1024 + hd * 64 + kcc * 8);
        kreg1 = *reinterpret_cast<const bf16x8*>(tb + (size_t)(32 + kr) * 3072 + 1024 + hd * 64 + kcc * 8);
        vreg0 = *reinterpret_cast<const bf16x8*>(tb + (size_t)(2 * vp) * 3072 + 2048 + hd * 64 + vd);
        vreg1 = *reinterpret_cast<const bf16x8*>(tb + (size_t)(2 * vp + 1) * 3072 + 2048 + hd * 64 + vd);
    };
    auto write_KV = [&](int buf) {
        bf16* Kb = &Klds[buf][0];
        bf16* Vb = &Vt[buf][0];
        const int kchunk = kcc ^ (kr & 7);
        *reinterpret_cast<bf16x8*>(&Kb[kr * 64 + kchunk * 8]) = kreg0;
        *reinterpret_cast<bf16x8*>(&Kb[(32 + kr) * 64 + kchunk * 8]) = kreg1;
#pragma unroll
        for (int jj = 0; jj < 8; ++jj) {
            int row = vd + jj;
            union { bf16 h2v[2]; uint32_t u; } pk;
            pk.h2v[0] = vreg0[jj]; pk.h2v[1] = vreg1[jj];
            int idx = row * 64 + (((vp >> 2) ^ (row & 7)) * 8) + (vp & 3) * 2;
            *reinterpret_cast<uint32_t*>(&Vb[idx]) = pk.u;
        }
    };

    load_tile(0);
    write_KV(0);
    if (nkt > 1) load_tile(1);
    __syncthreads();

    const int krow = kh * 32 + lane32;
    for (int kt = 0; kt < nkt; ++kt) {
        const int p = kt & 1;
        if (kt + 1 < nkt) write_KV(p ^ 1);

        // QK^T: two independent half-chains over d (halved dependent latency)
        f32x16 st_a, st_b;
#pragma unroll
        for (int i = 0; i < 16; ++i) { st_a[i] = 0.f; st_b[i] = 0.f; }
        bf16x8 kf[4];
#pragma unroll
        for (int s = 0; s < 4; ++s) {
            int ch = (2 * s + h) ^ (krow & 7);
            kf[s] = *reinterpret_cast<const bf16x8*>(&Klds[p][krow * 64 + ch * 8]);
        }
        __builtin_amdgcn_s_setprio(1);
        st_a = MFMA32(kf[0], qf[0], st_a);
        st_b = MFMA32(kf[2], qf[2], st_b);
        st_a = MFMA32(kf[1], qf[1], st_a);
        st_b = MFMA32(kf[3], qf[3], st_b);
        __builtin_amdgcn_s_setprio(0);
        f32x16 st = st_a + st_b;

        if (kt + 2 < nkt) load_tile(kt + 2);

        if (kt == qt) {
            const int q = qh * 32 + lane32;
#pragma unroll
            for (int reg = 0; reg < 16; ++reg) {
                int kloc = kh * 32 + 4 * h + (reg & 3) + 8 * (reg >> 2);
                if (kloc > q) st[reg] = NEGs;
            }
        }

        uint32_t wpk[4][2];
        float rs = 0.f;
#pragma unroll
        for (int g = 0; g < 4; ++g) {
            float p0 = exp2f_fast(st[4 * g + 0]);
            float p1 = exp2f_fast(st[4 * g + 1]);
            float p2 = exp2f_fast(st[4 * g + 2]);
            float p3 = exp2f_fast(st[4 * g + 3]);
            rs += (p0 + p1) + (p2 + p3);
            wpk[g][0] = pkbf(p0, p1);
            wpk[g][1] = pkbf(p2, p3);
        }
        lsum += rs;

        uint32_t opk[4][2];
#pragma unroll
        for (int g = 0; g < 4; ++g) {
            opk[g][0] = (uint32_t)__shfl_xor((int)wpk[g][0], 32, 64);
            opk[g][1] = (uint32_t)__shfl_xor((int)wpk[g][1], 32, 64);
        }

        bf16x8 pf[2];
#pragma unroll
        for (int s2 = 0; s2 < 2; ++s2) {
            union { uint32_t u[4]; bf16x8 v; } pu;
            const int g0 = 2 * s2, g1 = 2 * s2 + 1;
            pu.u[0] = h ? opk[g1][0] : wpk[g0][0];
            pu.u[1] = h ? opk[g1][1] : wpk[g0][1];
            pu.u[2] = h ? wpk[g1][0] : opk[g0][0];
            pu.u[3] = h ? wpk[g1][1] : opk[g0][1];
            pf[s2] = pu.v;
        }

        __builtin_amdgcn_s_setprio(1);
#pragma unroll
        for (int dt = 0; dt < 2; ++dt) {
            int vrow = dt * 32 + lane32;
#pragma unroll
            for (int s2 = 0; s2 < 2; ++s2) {
                int kc = (4 * kh + 2 * s2 + h) ^ (vrow & 7);
                bf16x8 vf = *reinterpret_cast<const bf16x8*>(&Vt[p][vrow * 64 + kc * 8]);
                oacc[dt] = MFMA32(pf[s2], vf, oacc[dt]);
            }
        }
        __builtin_amdgcn_s_setprio(0);

        __syncthreads();
    }

    lsum += __shfl_xor(lsum, 32, 64);
    if (l < 32) Lbuf[kh][qh][lane32] = lsum;

    float* Obuf = reinterpret_cast<float*>(&Klds[0][0]);   // [64 q][64 d] f32 = 16 KB
    if (kh == 1) {
#pragma unroll
        for (int dt = 0; dt < 2; ++dt)
#pragma unroll
            for (int reg = 0; reg < 16; ++reg) {
                int qrow = (reg & 3) + 8 * (reg >> 2) + 4 * h;
                Obuf[(qh * 32 + qrow) * 64 + dt * 32 + lane32] = oacc[dt][reg];
            }
    }
    __syncthreads();

    if (kh == 0) {
        float linv[16];
#pragma unroll
        for (int reg = 0; reg < 16; ++reg) {
            int qrow = (reg & 3) + 8 * (reg >> 2) + 4 * h;
            linv[reg] = 1.0f / (Lbuf[0][qh][qrow] + Lbuf[1][qh][qrow]);
        }
#pragma unroll
        for (int dt = 0; dt < 2; ++dt)
#pragma unroll
            for (int reg = 0; reg < 16; ++reg) {
                int qrow = (reg & 3) + 8 * (reg >> 2) + 4 * h;
                float v = (oacc[dt][reg] + Obuf[(qh * 32 + qrow) * 64 + dt * 32 + lane32]) * linv[reg];
                aout[(size_t)(b * S + qt * 64 + qh * 32 + qrow) * 1024 + hd * 64 + dt * 32 + lane32] =
                    (bf16)v;
            }
    }
}

extern "C" void kernel_launch(void* const* d_in, const int* in_sizes, int n_in,
                              void* d_out, int out_size, void* d_ws, size_t ws_size,
                              hipStream_t stream) {
    const float* x      = (const float*)d_in[0];
    const float* w_attn = (const float*)d_in[1];
    const float* b_attn = (const float*)d_in[2];
    const float* w_proj = (const float*)d_in[3];
    const float* b_proj = (const float*)d_in[4];
    float* out = (float*)d_out;
    char* ws = (char*)d_ws;

    const int Mtok = 4096, NX = 1024, N3 = 3072;
    bf16* xb   = (bf16*)(ws);
    bf16* wTa  = (bf16*)(ws + ((size_t)8 << 20));
    bf16* wTp  = (bf16*)(ws + ((size_t)14 << 20));
    bf16* qkv  = (bf16*)(ws + ((size_t)16 << 20));
    bf16* abuf = (bf16*)(ws + ((size_t)40 << 20));

    prep_kernel<<<dim3(8192), 256, 0, stream>>>(x, xb, w_attn, wTa, w_proj, wTp);
    gemm256_kernel<<<dim3(N3 / 256, Mtok / 256), 512, 0, stream>>>(xb, wTa, b_attn, qkv, Mtok, N3, NX);
    attn_kernel<<<dim3(32, 32), 256, 0, stream>>>(qkv, abuf);
    gemm64k_kernel<0><<<dim3(NX / 128, Mtok / 64), 256, 0, stream>>>(abuf, wTp, b_proj, out, Mtok, NX, NX);
}

// Round 12
// 168.242 us; speedup vs baseline: 1.1952x; 1.1952x over previous
//
#include <hip/hip_runtime.h>
#include <cstdint>
#include <cstddef>

// GPT-2 attention block, bf16 MFMA. B=2, S=2048, NX=1024, H=16, D=64.
// FINAL (revert-to-best): byte-identical to Round 7, the session's best
// measured configuration (168.80 us). R11's split-QK^T chains spilled
// (WRITE_SIZE 8->22MB) -- the attn kernel is register-critical at 64 VGPR;
// changes adding >=16 live VGPRs spill (R8: bound-induced; R11: pressure-
// induced). Plateau decomposition: ~42.7us harness fill (78% HBM, fixed) +
// gemm1 ~45 (schedule-bound; conflicts=0 with dur unchanged) + attn ~40
// (two MFMA architectures within 1us => chain-latency-bound at forced
// 4 blocks/CU) + gemm2 ~30 + prep ~11, partially overlapped.
// ws layout (48 MiB used):
//   [0,8M)    xb   : x as bf16            [4096][1024]
//   [8M,14M)  wTa  : w_attn^T as bf16     [3072][1024]
//   [14M,16M) wTp  : w_proj^T as bf16     [1024][1024]
//   [16M,40M) qkv  : bf16                 [4096][3072]
//   [40M,48M) abuf : attn out bf16        [4096][1024]

typedef __bf16 bf16;
typedef __bf16 bf16x8 __attribute__((ext_vector_type(8)));
typedef __bf16 bf16x4 __attribute__((ext_vector_type(4)));
typedef float f32x4 __attribute__((ext_vector_type(4)));
typedef float f32x16 __attribute__((ext_vector_type(16)));

#define MFMA16(a, b, c) __builtin_amdgcn_mfma_f32_16x16x32_bf16(a, b, c, 0, 0, 0)
#define MFMA32(a, b, c) __builtin_amdgcn_mfma_f32_32x32x16_bf16(a, b, c, 0, 0, 0)

typedef const __attribute__((address_space(1))) void* gas_ptr;
typedef __attribute__((address_space(3))) void* las_ptr;
__device__ __forceinline__ void async16(const void* g, void* l) {
    __builtin_amdgcn_global_load_lds((gas_ptr)g, (las_ptr)l, 16, 0, 0);
}
__device__ __forceinline__ float exp2f_fast(float x) { return __builtin_amdgcn_exp2f(x); }
__device__ __forceinline__ uint32_t pkbf(float a, float b) {
    union { bf16 x[2]; uint32_t u; } t;
    t.x[0] = (bf16)a; t.x[1] = (bf16)b;
    return t.u;
}

// ---------------- fused prep: cvt x->bf16 + transpose both weights ----------------
__global__ __launch_bounds__(256) void prep_kernel(const float* __restrict__ x, bf16* __restrict__ xb,
                                                   const float* __restrict__ wa, bf16* __restrict__ wTa,
                                                   const float* __restrict__ wp, bf16* __restrict__ wTp) {
    __shared__ float tile[32][33];
    const int bid = blockIdx.x, tid = threadIdx.x;
    if (bid < 4096) {
        int i = (bid * 256 + tid) * 4;
        float4 v = *reinterpret_cast<const float4*>(x + i);
        bf16x4 o;
        o[0] = (bf16)v.x; o[1] = (bf16)v.y; o[2] = (bf16)v.z; o[3] = (bf16)v.w;
        *reinterpret_cast<bf16x4*>(xb + i) = o;
        return;
    }
    const float* in; bf16* out; int N, t;
    if (bid < 7168) { t = bid - 4096; in = wa; out = wTa; N = 3072; }
    else            { t = bid - 7168; in = wp; out = wTp; N = 1024; }
    const int K = 1024;
    int bx = t % (N >> 5), by = t / (N >> 5);
    int n0 = bx * 32, k0 = by * 32, tx = tid & 31, ty = tid >> 5;
#pragma unroll
    for (int i = 0; i < 32; i += 8)
        tile[ty + i][tx] = in[(size_t)(k0 + ty + i) * N + n0 + tx];
    __syncthreads();
#pragma unroll
    for (int i = 0; i < 32; i += 8)
        out[(size_t)(n0 + ty + i) * K + k0 + tx] = (bf16)tile[tx][ty + i];
}

// ---------------- bf16 GEMM 128x128, BK=32, dbuf, packed conflict-free LDS ----------------
template <int OUT_BF16>
__global__ __launch_bounds__(256) void gemm_kernel(const bf16* __restrict__ A,
                                                   const bf16* __restrict__ Bt,
                                                   const float* __restrict__ bias,
                                                   void* __restrict__ Cout,
                                                   int M, int N, int K) {
    __shared__ bf16 Alds[2][128 * 32];
    __shared__ bf16 Blds[2][128 * 32];
    const int tid = threadIdx.x;
    const int w = tid >> 6, l = tid & 63;
    const int lane16 = l & 15, quad = l >> 4;
    const int wr = w >> 1, wc = w & 1;

    const int nwg = gridDim.x * gridDim.y;
    const int lin = blockIdx.x + gridDim.x * blockIdx.y;
    const int q8 = nwg >> 3;
    const int swz = (lin & 7) * q8 + (lin >> 3);
    const int bx = swz % gridDim.x, by = swz / gridDim.x;
    const int row0 = by * 128, col0 = bx * 128;

    int grs[2], gks[2];
#pragma unroll
    for (int c = 0; c < 2; ++c) {
        int idx = c * 256 + tid;
        int R = idx >> 3, pos = idx & 7;
        int pos2 = pos ^ (R & 7);
        grs[c] = 2 * R + (pos2 >> 2);
        gks[c] = (pos2 & 3) * 8;
    }

    f32x4 zero4 = {0.f, 0.f, 0.f, 0.f};
    f32x4 acc[4][4];
#pragma unroll
    for (int i = 0; i < 4; ++i)
#pragma unroll
        for (int j = 0; j < 4; ++j) acc[i][j] = zero4;

    auto stage = [&](int buf, int k0) {
#pragma unroll
        for (int c = 0; c < 2; ++c) {
            int idx = c * 256 + tid;
            async16(A + (size_t)(row0 + grs[c]) * K + k0 + gks[c], &Alds[buf][idx * 8]);
            async16(Bt + (size_t)(col0 + grs[c]) * K + k0 + gks[c], &Blds[buf][idx * 8]);
        }
    };

    stage(0, 0);
    const int niter = K >> 5;
    for (int it = 0; it < niter; ++it) {
        const int cur = it & 1;
        __syncthreads();
        if (it + 1 < niter) stage(cur ^ 1, (it + 1) << 5);
        bf16x8 af[4], bfr[4];
#pragma unroll
        for (int i = 0; i < 4; ++i) {
            int gra = 64 * wr + 16 * i + lane16;
            int Ra = gra >> 1;
            int pa = ((gra & 1) * 4 + quad) ^ (Ra & 7);
            af[i] = *reinterpret_cast<const bf16x8*>(&Alds[cur][Ra * 64 + pa * 8]);
            int grb = 64 * wc + 16 * i + lane16;
            int Rb = grb >> 1;
            int pb = ((grb & 1) * 4 + quad) ^ (Rb & 7);
            bfr[i] = *reinterpret_cast<const bf16x8*>(&Blds[cur][Rb * 64 + pb * 8]);
        }
#pragma unroll
        for (int i = 0; i < 4; ++i)
#pragma unroll
            for (int j = 0; j < 4; ++j) acc[i][j] = MFMA16(af[i], bfr[j], acc[i][j]);
    }

#pragma unroll
    for (int i = 0; i < 4; ++i)
#pragma unroll
        for (int j = 0; j < 4; ++j)
#pragma unroll
            for (int r = 0; r < 4; ++r) {
                int row = row0 + 64 * wr + 16 * i + quad * 4 + r;
                int col = col0 + 64 * wc + 16 * j + lane16;
                float v = acc[i][j][r] + bias[col];
                if (OUT_BF16)
                    reinterpret_cast<bf16*>(Cout)[(size_t)row * N + col] = (bf16)v;
                else
                    reinterpret_cast<float*>(Cout)[(size_t)row * N + col] = v;
            }
}

// ---------------- bf16 GEMM 64x128, BK=64, XOR-swizzled LDS, dbuf ----------------
template <int OUT_BF16>
__global__ __launch_bounds__(256) void gemm64k_kernel(const bf16* __restrict__ A,
                                                      const bf16* __restrict__ Bt,
                                                      const float* __restrict__ bias,
                                                      void* __restrict__ Cout,
                                                      int M, int N, int K) {
    __shared__ bf16 Alds[2][64 * 64];
    __shared__ bf16 Blds[2][128 * 64];
    const int tid = threadIdx.x;
    const int w = tid >> 6, l = tid & 63;
    const int lane16 = l & 15, quad = l >> 4;
    const int wr = w >> 1, wc = w & 1;
    const int row0 = blockIdx.y * 64, col0 = blockIdx.x * 128;

    f32x4 zero4 = {0.f, 0.f, 0.f, 0.f};
    f32x4 acc[2][4];
#pragma unroll
    for (int i = 0; i < 2; ++i)
#pragma unroll
        for (int j = 0; j < 4; ++j) acc[i][j] = zero4;

    auto stage = [&](int buf, int k0) {
#pragma unroll
        for (int c = 0; c < 2; ++c) {
            int idx = c * 256 + tid;
            int r = idx >> 3, cc = idx & 7, gc = cc ^ (r & 7);
            async16(A + (size_t)(row0 + r) * K + k0 + gc * 8, &Alds[buf][idx * 8]);
        }
#pragma unroll
        for (int c = 0; c < 4; ++c) {
            int idx = c * 256 + tid;
            int r = idx >> 3, cc = idx & 7, gc = cc ^ (r & 7);
            async16(Bt + (size_t)(col0 + r) * K + k0 + gc * 8, &Blds[buf][idx * 8]);
        }
    };

    stage(0, 0);
    const int niter = K >> 6;
    for (int it = 0; it < niter; ++it) {
        const int cur = it & 1;
        __syncthreads();
        if (it + 1 < niter) stage(cur ^ 1, (it + 1) << 6);
        bf16x8 af[2][2], bfr[4][2];
#pragma unroll
        for (int i = 0; i < 2; ++i) {
            int r = 32 * wr + 16 * i + lane16;
#pragma unroll
            for (int ks = 0; ks < 2; ++ks) {
                int cc = (quad + 4 * ks) ^ (r & 7);
                af[i][ks] = *reinterpret_cast<const bf16x8*>(&Alds[cur][r * 64 + cc * 8]);
            }
        }
#pragma unroll
        for (int j = 0; j < 4; ++j) {
            int r = 64 * wc + 16 * j + lane16;
#pragma unroll
            for (int ks = 0; ks < 2; ++ks) {
                int cc = (quad + 4 * ks) ^ (r & 7);
                bfr[j][ks] = *reinterpret_cast<const bf16x8*>(&Blds[cur][r * 64 + cc * 8]);
            }
        }
#pragma unroll
        for (int ks = 0; ks < 2; ++ks)
#pragma unroll
            for (int i = 0; i < 2; ++i)
#pragma unroll
                for (int j = 0; j < 4; ++j) acc[i][j] = MFMA16(af[i][ks], bfr[j][ks], acc[i][j]);
    }

#pragma unroll
    for (int i = 0; i < 2; ++i)
#pragma unroll
        for (int j = 0; j < 4; ++j)
#pragma unroll
            for (int r = 0; r < 4; ++r) {
                int row = row0 + 32 * wr + 16 * i + quad * 4 + r;
                int col = col0 + 64 * wc + 16 * j + lane16;
                float v = acc[i][j][r] + bias[col];
                if (OUT_BF16)
                    reinterpret_cast<bf16*>(Cout)[(size_t)row * N + col] = (bf16)v;
                else
                    reinterpret_cast<float*>(Cout)[(size_t)row * N + col] = v;
            }
}

// ---------------- flash attention: 32x32 MFMA + in-reg softmax (R6 math, R4 staging) ----------------
__global__ __launch_bounds__(256, 4) void attn_kernel(const bf16* __restrict__ qkv,
                                                      bf16* __restrict__ aout) {
    const int S = 2048;
    const int bh = blockIdx.x;
    const int b = bh >> 4, hd = bh & 15;
    const int rr = blockIdx.y >> 3, j = blockIdx.y & 7;
    const int qt = (rr == 0) ? (31 - j) : (rr == 1) ? (16 + j) : (rr == 2) ? (15 - j) : j;
    const int nkt = qt + 1;
    const int tid = threadIdx.x, w = tid >> 6, l = tid & 63;
    const int lane32 = l & 31, h = l >> 5;
    const int qh = w & 1, kh = w >> 1;

    __shared__ bf16 Klds[2][64 * 64];   // [k][d] swizzled; re-used as f32 Obuf post-loop
    __shared__ bf16 Vt[2][64 * 64];     // [d][k] swizzled
    __shared__ float Lbuf[2][2][32];    // [kh][qh][q-row]

    const bf16* base = qkv + (size_t)b * S * 3072;
    const float qscale = 0.125f * 1.4426950408889634f;
    const float NEGs = -10000.0f * 1.4426950408889634f;

    bf16x8 qf[4];
    {
        const bf16* qp = base + (size_t)(qt * 64 + qh * 32 + lane32) * 3072 + hd * 64;
#pragma unroll
        for (int s = 0; s < 4; ++s) {
            bf16x8 t = *reinterpret_cast<const bf16x8*>(qp + s * 16 + h * 8);
#pragma unroll
            for (int jj = 0; jj < 8; ++jj) t[jj] = (bf16)((float)t[jj] * qscale);
            qf[s] = t;
        }
    }

    f32x16 oacc[2];
#pragma unroll
    for (int dt = 0; dt < 2; ++dt)
#pragma unroll
        for (int i = 0; i < 16; ++i) oacc[dt][i] = 0.f;
    float lsum = 0.f;

    const int kr = tid >> 3, kcc = tid & 7;
    const int vp = tid & 31, vd = (tid >> 5) * 8;
    bf16x8 kreg0, kreg1, vreg0, vreg1;
    auto load_tile = [&](int kt) {
        const bf16* tb = base + (size_t)(kt * 64) * 3072;
        kreg0 = *reinterpret_cast<const bf16x8*>(tb + (size_t)kr * 3072 + 1024 + hd * 64 + kcc * 8);
        kreg1 = *reinterpret_cast<const bf16x8*>(tb + (size_t)(32 + kr) * 3072 + 1024 + hd * 64 + kcc * 8);
        vreg0 = *reinterpret_cast<const bf16x8*>(tb + (size_t)(2 * vp) * 3072 + 2048 + hd * 64 + vd);
        vreg1 = *reinterpret_cast<const bf16x8*>(tb + (size_t)(2 * vp + 1) * 3072 + 2048 + hd * 64 + vd);
    };
    auto write_KV = [&](int buf) {
        bf16* Kb = &Klds[buf][0];
        bf16* Vb = &Vt[buf][0];
        const int kchunk = kcc ^ (kr & 7);
        *reinterpret_cast<bf16x8*>(&Kb[kr * 64 + kchunk * 8]) = kreg0;
        *reinterpret_cast<bf16x8*>(&Kb[(32 + kr) * 64 + kchunk * 8]) = kreg1;
#pragma unroll
        for (int jj = 0; jj < 8; ++jj) {
            int row = vd + jj;
            union { bf16 h2v[2]; uint32_t u; } pk;
            pk.h2v[0] = vreg0[jj]; pk.h2v[1] = vreg1[jj];
            int idx = row * 64 + (((vp >> 2) ^ (row & 7)) * 8) + (vp & 3) * 2;
            *reinterpret_cast<uint32_t*>(&Vb[idx]) = pk.u;
        }
    };

    load_tile(0);
    write_KV(0);
    if (nkt > 1) load_tile(1);
    __syncthreads();

    const int krow = kh * 32 + lane32;
    for (int kt = 0; kt < nkt; ++kt) {
        const int p = kt & 1;
        if (kt + 1 < nkt) write_KV(p ^ 1);

        f32x16 st;
#pragma unroll
        for (int i = 0; i < 16; ++i) st[i] = 0.f;
        __builtin_amdgcn_s_setprio(1);
#pragma unroll
        for (int s = 0; s < 4; ++s) {
            int ch = (2 * s + h) ^ (krow & 7);
            bf16x8 kf = *reinterpret_cast<const bf16x8*>(&Klds[p][krow * 64 + ch * 8]);
            st = MFMA32(kf, qf[s], st);
        }
        __builtin_amdgcn_s_setprio(0);

        if (kt + 2 < nkt) load_tile(kt + 2);

        if (kt == qt) {
            const int q = qh * 32 + lane32;
#pragma unroll
            for (int reg = 0; reg < 16; ++reg) {
                int kloc = kh * 32 + 4 * h + (reg & 3) + 8 * (reg >> 2);
                if (kloc > q) st[reg] = NEGs;
            }
        }

        uint32_t wpk[4][2];
        float rs = 0.f;
#pragma unroll
        for (int g = 0; g < 4; ++g) {
            float p0 = exp2f_fast(st[4 * g + 0]);
            float p1 = exp2f_fast(st[4 * g + 1]);
            float p2 = exp2f_fast(st[4 * g + 2]);
            float p3 = exp2f_fast(st[4 * g + 3]);
            rs += (p0 + p1) + (p2 + p3);
            wpk[g][0] = pkbf(p0, p1);
            wpk[g][1] = pkbf(p2, p3);
        }
        lsum += rs;

        uint32_t opk[4][2];
#pragma unroll
        for (int g = 0; g < 4; ++g) {
            opk[g][0] = (uint32_t)__shfl_xor((int)wpk[g][0], 32, 64);
            opk[g][1] = (uint32_t)__shfl_xor((int)wpk[g][1], 32, 64);
        }

        bf16x8 pf[2];
#pragma unroll
        for (int s2 = 0; s2 < 2; ++s2) {
            union { uint32_t u[4]; bf16x8 v; } pu;
            const int g0 = 2 * s2, g1 = 2 * s2 + 1;
            pu.u[0] = h ? opk[g1][0] : wpk[g0][0];
            pu.u[1] = h ? opk[g1][1] : wpk[g0][1];
            pu.u[2] = h ? wpk[g1][0] : opk[g0][0];
            pu.u[3] = h ? wpk[g1][1] : opk[g0][1];
            pf[s2] = pu.v;
        }

        __builtin_amdgcn_s_setprio(1);
#pragma unroll
        for (int dt = 0; dt < 2; ++dt) {
            int vrow = dt * 32 + lane32;
#pragma unroll
            for (int s2 = 0; s2 < 2; ++s2) {
                int kc = (4 * kh + 2 * s2 + h) ^ (vrow & 7);
                bf16x8 vf = *reinterpret_cast<const bf16x8*>(&Vt[p][vrow * 64 + kc * 8]);
                oacc[dt] = MFMA32(pf[s2], vf, oacc[dt]);
            }
        }
        __builtin_amdgcn_s_setprio(0);

        __syncthreads();
    }

    lsum += __shfl_xor(lsum, 32, 64);
    if (l < 32) Lbuf[kh][qh][lane32] = lsum;

    float* Obuf = reinterpret_cast<float*>(&Klds[0][0]);   // [64 q][64 d] f32 = 16 KB
    if (kh == 1) {
#pragma unroll
        for (int dt = 0; dt < 2; ++dt)
#pragma unroll
            for (int reg = 0; reg < 16; ++reg) {
                int qrow = (reg & 3) + 8 * (reg >> 2) + 4 * h;
                Obuf[(qh * 32 + qrow) * 64 + dt * 32 + lane32] = oacc[dt][reg];
            }
    }
    __syncthreads();

    if (kh == 0) {
        float linv[16];
#pragma unroll
        for (int reg = 0; reg < 16; ++reg) {
            int qrow = (reg & 3) + 8 * (reg >> 2) + 4 * h;
            linv[reg] = 1.0f / (Lbuf[0][qh][qrow] + Lbuf[1][qh][qrow]);
        }
#pragma unroll
        for (int dt = 0; dt < 2; ++dt)
#pragma unroll
            for (int reg = 0; reg < 16; ++reg) {
                int qrow = (reg & 3) + 8 * (reg >> 2) + 4 * h;
                float v = (oacc[dt][reg] + Obuf[(qh * 32 + qrow) * 64 + dt * 32 + lane32]) * linv[reg];
                aout[(size_t)(b * S + qt * 64 + qh * 32 + qrow) * 1024 + hd * 64 + dt * 32 + lane32] =
                    (bf16)v;
            }
    }
}

extern "C" void kernel_launch(void* const* d_in, const int* in_sizes, int n_in,
                              void* d_out, int out_size, void* d_ws, size_t ws_size,
                              hipStream_t stream) {
    const float* x      = (const float*)d_in[0];
    const float* w_attn = (const float*)d_in[1];
    const float* b_attn = (const float*)d_in[2];
    const float* w_proj = (const float*)d_in[3];
    const float* b_proj = (const float*)d_in[4];
    float* out = (float*)d_out;
    char* ws = (char*)d_ws;

    const int Mtok = 4096, NX = 1024, N3 = 3072;
    bf16* xb   = (bf16*)(ws);
    bf16* wTa  = (bf16*)(ws + ((size_t)8 << 20));
    bf16* wTp  = (bf16*)(ws + ((size_t)14 << 20));
    bf16* qkv  = (bf16*)(ws + ((size_t)16 << 20));
    bf16* abuf = (bf16*)(ws + ((size_t)40 << 20));

    prep_kernel<<<dim3(8192), 256, 0, stream>>>(x, xb, w_attn, wTa, w_proj, wTp);
    gemm_kernel<1><<<dim3(N3 / 128, Mtok / 128), 256, 0, stream>>>(xb, wTa, b_attn, qkv, Mtok, N3, NX);
    attn_kernel<<<dim3(32, 32), 256, 0, stream>>>(qkv, abuf);
    gemm64k_kernel<0><<<dim3(NX / 128, Mtok / 64), 256, 0, stream>>>(abuf, wTp, b_proj, out, Mtok, NX, NX);
}